// Round 6
// baseline (4840.405 us; speedup 1.0000x reference)
//
#include <hip/hip_runtime.h>
#include <hip/hip_bf16.h>
#include <math.h>

// ---------------- problem constants ----------------
#define NTOK 401408              // 8*1024*49 tokens
#define NWIN 8192                // 8*1024 windows
#define NCHUNK 4
#define TOK_PER_CHUNK (NTOK / NCHUNK)   // 100352
#define WIN_PER_CHUNK (NWIN / NCHUNK)   // 2048

typedef __attribute__((ext_vector_type(8))) short bf16x8_t;
typedef __attribute__((ext_vector_type(4))) float f32x4_t;

__device__ __forceinline__ float bf2f(unsigned int u) {
    return __uint_as_float(u << 16);
}
__device__ __forceinline__ unsigned short f2bf(float f) {
    unsigned int x = __float_as_uint(f);
    x += 0x7fffu + ((x >> 16) & 1u);   // RNE
    return (unsigned short)(x >> 16);
}
__device__ __forceinline__ unsigned int pack2bf(float a, float b) {
    return (unsigned int)f2bf(a) | ((unsigned int)f2bf(b) << 16);
}

// ---------------- weight transpose + bf16 cast:  WT[n][k] = W[k][n] ----------------
__global__ void wt_kernel(const float* __restrict__ W, unsigned short* __restrict__ WT,
                          int K, int N) {
    int i = blockIdx.x * 256 + threadIdx.x;
    if (i >= N * K) return;
    int n = i / K, k = i - n * K;
    WT[i] = f2bf(W[(size_t)k * N + n]);
}

// ---------------- bias(+mask) table baked into MFMA C-fragment layout ----------------
__global__ void bias_kernel(const float* __restrict__ bt0, const float* __restrict__ bt1,
                            float* __restrict__ bm) {
    int idx = blockIdx.x * 256 + threadIdx.x;   // 0..24575
    int variant = blockIdx.y;
    const float* bt = variant ? bt1 : bt0;
    int r = idx & 3, lane = (idx >> 2) & 63, ni = (idx >> 8) & 3, mi = (idx >> 10) & 3, h = idx >> 12;
    int g = lane >> 4;
    int q = ni * 16 + (lane & 15);
    int k = mi * 16 + g * 4 + r;
    float v = 0.f;
    if (q < 49 && k < 49) {
        int qh = q / 7, qw = q - qh * 7, kh = k / 7, kw = k - kh * 7;
        v = bt[((qh - kh + 6) * 13 + (qw - kw + 6)) * 6 + h];
        if (variant) {
            int rq = 2 * (qh >= 4) + (qw >= 4), rk = 2 * (kh >= 4) + (kw >= 4);
            if (rq != rk) v -= 100.f;
        }
    }
    bm[(size_t)variant * 24576 + idx] = v;
}

// ---------------- LayerNorm over 192 channels, 1 wave / token ----------------
template<int IN_BF16, int ROLL>
__global__ __launch_bounds__(256) void ln_kernel(const void* __restrict__ in,
                                                 unsigned short* __restrict__ out,
                                                 const float* __restrict__ g,
                                                 const float* __restrict__ b) {
    int tok  = blockIdx.x * 4 + (threadIdx.x >> 6);
    int lane = threadIdx.x & 63;
    int src = tok;
    if (ROLL) {
        int win = tok / 49, p2 = tok - win * 49;
        int h = p2 / 7, w = p2 - h * 7;
        int h2 = h + 3; if (h2 >= 7) h2 -= 7;
        int w2 = w + 3; if (w2 >= 7) w2 -= 7;
        src = win * 49 + h2 * 7 + w2;
    }
    float x0, x1, x2;
    if (IN_BF16) {
        const unsigned short* p = (const unsigned short*)in + (size_t)src * 192;
        x0 = bf2f(p[lane]); x1 = bf2f(p[lane + 64]); x2 = bf2f(p[lane + 128]);
    } else {
        const float* p = (const float*)in + (size_t)src * 192;
        x0 = p[lane]; x1 = p[lane + 64]; x2 = p[lane + 128];
    }
    float s  = x0 + x1 + x2;
    float sq = x0 * x0 + x1 * x1 + x2 * x2;
    for (int o = 32; o; o >>= 1) { s += __shfl_xor(s, o); sq += __shfl_xor(sq, o); }
    float m   = s * (1.f / 192.f);
    float var = sq * (1.f / 192.f) - m * m;
    float r   = rsqrtf(var + 1e-5f);
    unsigned short* q = out + (size_t)tok * 192;
    q[lane]       = f2bf((x0 - m) * r * g[lane]       + b[lane]);
    q[lane + 64]  = f2bf((x1 - m) * r * g[lane + 64]  + b[lane + 64]);
    q[lane + 128] = f2bf((x2 - m) * r * g[lane + 128] + b[lane + 128]);
}

// ---------------- epilogue codes ----------------
#define EP_QKV        0   // + bias, Q cols pre-scaled by 1/sqrt(dh) -> bf16 (ld = NDIM)
#define EP_PROJ1      1   // + bias + f32 residual (linear) -> bf16
#define EP_PROJ2      2   // + bias + f32 residual (roll-read) -> bf16
#define EP_MLP1       3   // + bias, exact GELU -> bf16 (ld = NDIM)
#define EP_MLP2_TRUNK 4   // + bias + bf16 residual -> f32 trunk, LINEAR write
#define EP_MLP2_OUT   5   // + bias + bf16 residual -> f32 d_out with final roll (w+3, c+3)

template<int NDIM, int EP>
__device__ __forceinline__ void gemm_epilogue(f32x4_t acc[4][6],
                                              const float* __restrict__ bias,
                                              const void* __restrict__ res,
                                              void* __restrict__ out,
                                              int rowBase, int colBase,
                                              int wm, int wn, int kq, int lr, int row0) {
    const float* resf = (const float*)res;
    const unsigned short* resb = (const unsigned short*)res;
    #pragma unroll
    for (int mi = 0; mi < 4; ++mi) {
        #pragma unroll
        for (int ni = 0; ni < 6; ++ni) {
            int col = colBase + wn * 96 + ni * 16 + lr;
            float bcol = bias[col];
            #pragma unroll
            for (int r = 0; r < 4; ++r) {
                int rloc = rowBase + wm * 64 + mi * 16 + kq * 4 + r;
                float v = acc[mi][ni][r] + bcol;
                if (EP == EP_QKV) {
                    if (colBase == 0) v *= 0.17677669529663687f;   // pre-scale Q
                    ((unsigned short*)out)[(size_t)rloc * NDIM + col] = f2bf(v);
                } else if (EP == EP_PROJ1) {
                    v += resf[(size_t)rloc * 192 + col];
                    ((unsigned short*)out)[(size_t)rloc * 192 + col] = f2bf(v);
                } else if (EP == EP_PROJ2) {
                    int win = rloc / 49, p2 = rloc - win * 49;
                    int h = p2 / 7, w = p2 - h * 7;
                    int h2 = h + 3; if (h2 >= 7) h2 -= 7;
                    int w2 = w + 3; if (w2 >= 7) w2 -= 7;
                    v += resf[((size_t)win * 49 + h2 * 7 + w2) * 192 + col];
                    ((unsigned short*)out)[(size_t)rloc * 192 + col] = f2bf(v);
                } else if (EP == EP_MLP1) {
                    float gl = 0.5f * v * (1.f + erff(v * 0.70710678118654752f));
                    ((unsigned short*)out)[(size_t)rloc * NDIM + col] = f2bf(gl);
                } else if (EP == EP_MLP2_TRUNK) {
                    v += bf2f((unsigned int)resb[(size_t)rloc * 192 + col]);
                    int grow = row0 + rloc;
                    ((float*)out)[(size_t)grow * 192 + col] = v;   // linear trunk
                } else {  // EP_MLP2_OUT
                    v += bf2f((unsigned int)resb[(size_t)rloc * 192 + col]);
                    int grow = row0 + rloc;
                    int win = grow / 49, p2 = grow - win * 49;
                    int h = p2 / 7, w = p2 - h * 7;
                    int w2 = w + 3; if (w2 >= 7) w2 -= 7;
                    int c2 = col + 3; if (c2 >= 192) c2 -= 192;
                    ((float*)out)[((size_t)win * 49 + h * 7 + w2) * 192 + c2] = v;
                }
            }
        }
    }
}

// ---------------- K=192 GEMM: A-tile resident in LDS, B direct from global ----------------
// Tile 128 x 192, 4 waves (2m x 2n), per-wave 64x96 = 4x6 fragments. ONE barrier per block.
// Block order: y-fastest (A-row reuse across y) + bijective XCD chunking (grid % 8 == 0).
template<int NDIM, int NY, int EP>
__global__ __launch_bounds__(256) void gemm192_kernel(const unsigned short* __restrict__ A,
                                                      const unsigned short* __restrict__ WT,
                                                      const float* __restrict__ bias,
                                                      const void* __restrict__ res,
                                                      void* __restrict__ out,
                                                      int row0) {
    __shared__ __align__(16) unsigned short As[128][200];   // stride 400B: banks spread by 4
    int tid = threadIdx.x;
    int nwg = gridDim.x;
    int id = blockIdx.x;
    int id2 = (id & 7) * (nwg >> 3) + (id >> 3);    // XCD-chunked (nwg % 8 == 0)
    int by = id2 % NY, bx = id2 / NY;               // y fastest
    int rowBase = bx * 128;
    int colBase = by * 192;

    // stage A once: 128 rows x 24 chunks (16B) = 3072 chunks, 12 per thread
    #pragma unroll
    for (int t = 0; t < 12; ++t) {
        int idx = tid + t * 256;
        int r = idx / 24, pp = idx - r * 24;
        *(uint4*)&As[r][pp * 8] = *(const uint4*)(A + (size_t)(rowBase + r) * 192 + pp * 8);
    }
    __syncthreads();

    int wave = tid >> 6, lane = tid & 63;
    int wm = wave >> 1, wn = wave & 1;
    int kq = lane >> 4, lr = lane & 15;

    const unsigned short* Bp = WT + (size_t)(colBase + wn * 96 + lr) * 192 + kq * 8;
    f32x4_t acc[4][6] = {};
    #pragma unroll
    for (int ks = 0; ks < 6; ++ks) {
        bf16x8_t bfr[6], afr[4];
        #pragma unroll
        for (int ni = 0; ni < 6; ++ni)
            bfr[ni] = *(const bf16x8_t*)(Bp + ni * 16 * 192 + ks * 32);
        #pragma unroll
        for (int mi = 0; mi < 4; ++mi)
            afr[mi] = *(const bf16x8_t*)&As[wm * 64 + mi * 16 + lr][ks * 32 + kq * 8];
        #pragma unroll
        for (int mi = 0; mi < 4; ++mi)
            #pragma unroll
            for (int ni = 0; ni < 6; ++ni)
                acc[mi][ni] = __builtin_amdgcn_mfma_f32_16x16x32_bf16(
                    afr[mi], bfr[ni], acc[mi][ni], 0, 0, 0);
    }

    gemm_epilogue<NDIM, EP>(acc, bias, res, out, rowBase, colBase, wm, wn, kq, lr, row0);
}

// ---------------- K=768 GEMM (MLP2): BK=96 reg-prefetch, B direct from global ----------------
template<int EP>
__global__ __launch_bounds__(256) void gemm768_kernel(const unsigned short* __restrict__ A,
                                                      const unsigned short* __restrict__ WT,
                                                      const float* __restrict__ bias,
                                                      const void* __restrict__ res,
                                                      void* __restrict__ out,
                                                      int row0) {
    __shared__ __align__(16) unsigned short As[128][104];   // 96+8 pad: stride 208B
    int tid = threadIdx.x;
    int nwg = gridDim.x;
    int id = blockIdx.x;
    int bx = (id & 7) * (nwg >> 3) + (id >> 3);
    int rowBase = bx * 128;

    int wave = tid >> 6, lane = tid & 63;
    int wm = wave >> 1, wn = wave & 1;
    int kq = lane >> 4, lr = lane & 15;

    const unsigned short* Bp = WT + (size_t)(wn * 96 + lr) * 768 + kq * 8;
    f32x4_t acc[4][6] = {};

    // K-slice = 128 rows x 12 chunks (16B) = 1536 chunks, 6 per thread
    uint4 st[6];
    #pragma unroll
    for (int j = 0; j < 6; ++j) {
        int idx = tid + j * 256;
        int r = idx / 12, c = idx - r * 12;
        st[j] = *(const uint4*)(A + (size_t)(rowBase + r) * 768 + c * 8);
    }

    #pragma unroll
    for (int kt = 0; kt < 8; ++kt) {
        __syncthreads();   // previous buffer fully consumed
        #pragma unroll
        for (int j = 0; j < 6; ++j) {
            int idx = tid + j * 256;
            int r = idx / 12, c = idx - r * 12;
            *(uint4*)&As[r][c * 8] = st[j];
        }
        if (kt < 7) {       // prefetch next K-slice; lands during compute below
            int k0 = (kt + 1) * 96;
            #pragma unroll
            for (int j = 0; j < 6; ++j) {
                int idx = tid + j * 256;
                int r = idx / 12, c = idx - r * 12;
                st[j] = *(const uint4*)(A + (size_t)(rowBase + r) * 768 + k0 + c * 8);
            }
        }
        __syncthreads();
        #pragma unroll
        for (int ks = 0; ks < 3; ++ks) {
            bf16x8_t bfr[6], afr[4];
            #pragma unroll
            for (int ni = 0; ni < 6; ++ni)
                bfr[ni] = *(const bf16x8_t*)(Bp + (size_t)ni * 16 * 768 + kt * 96 + ks * 32);
            #pragma unroll
            for (int mi = 0; mi < 4; ++mi)
                afr[mi] = *(const bf16x8_t*)&As[wm * 64 + mi * 16 + lr][ks * 32 + kq * 8];
            #pragma unroll
            for (int mi = 0; mi < 4; ++mi)
                #pragma unroll
                for (int ni = 0; ni < 6; ++ni)
                    acc[mi][ni] = __builtin_amdgcn_mfma_f32_16x16x32_bf16(
                        afr[mi], bfr[ni], acc[mi][ni], 0, 0, 0);
        }
    }

    gemm_epilogue<192, EP>(acc, bias, res, out, rowBase, 0, wm, wn, kq, lr, row0);
}

// ---------------- MFMA window attention: 1 wave per (head, window) ----------------
__global__ __launch_bounds__(64) void attn_kernel(const unsigned short* __restrict__ qkv,
                                                  const float* __restrict__ bm,  // [6][4][4][64][4]
                                                  unsigned short* __restrict__ outp,
                                                  int win0) {
    __shared__ unsigned short P[64][72];
    __shared__ unsigned short VT[32][72];
    int head = blockIdx.x, wloc = blockIdx.y;
    int lane = threadIdx.x;
    int g = lane >> 4, lr = lane & 15;
    const unsigned short* base = qkv + (size_t)wloc * 49 * 576;

    // stage V^T (tok>=49 -> zeros)
    for (int i = lane; i < 256; i += 64) {
        int tok = i >> 2, seg = i & 3;
        uint4 u = make_uint4(0u, 0u, 0u, 0u);
        if (tok < 49)
            u = *(const uint4*)(base + (size_t)tok * 576 + 384 + head * 32 + seg * 8);
        const unsigned short* us = (const unsigned short*)&u;
        #pragma unroll
        for (int j = 0; j < 8; ++j) VT[seg * 8 + j][tok] = us[j];
    }

    bf16x8_t kf[4], qf[4];
    #pragma unroll
    for (int mi = 0; mi < 4; ++mi) {
        int tok = mi * 16 + lr; if (tok > 48) tok = 48;
        kf[mi] = *(const bf16x8_t*)(base + (size_t)tok * 576 + 192 + head * 32 + g * 8);
    }
    #pragma unroll
    for (int ni = 0; ni < 4; ++ni) {
        int tok = ni * 16 + lr; if (tok > 48) tok = 48;
        qf[ni] = *(const bf16x8_t*)(base + (size_t)tok * 576 + head * 32 + g * 8);
    }

    const float* bmh = bm + (size_t)head * 4096;
    f32x4_t acc[4][4];
    #pragma unroll
    for (int mi = 0; mi < 4; ++mi)
        #pragma unroll
        for (int ni = 0; ni < 4; ++ni)
            acc[mi][ni] = *(const f32x4_t*)(bmh + ((mi * 4 + ni) * 64 + lane) * 4);
    #pragma unroll
    for (int mi = 0; mi < 4; ++mi)
        #pragma unroll
        for (int ni = 0; ni < 4; ++ni)
            acc[mi][ni] = __builtin_amdgcn_mfma_f32_16x16x32_bf16(kf[mi], qf[ni], acc[mi][ni], 0, 0, 0);

    float inv[4];
    #pragma unroll
    for (int ni = 0; ni < 4; ++ni) {
        float mx = -1e30f;
        #pragma unroll
        for (int mi = 0; mi < 3; ++mi)
            #pragma unroll
            for (int r = 0; r < 4; ++r) mx = fmaxf(mx, acc[mi][ni][r]);
        mx = fmaxf(mx, (g == 0) ? acc[3][ni][0] : -1e30f);
        mx = fmaxf(mx, __shfl_xor(mx, 16));
        mx = fmaxf(mx, __shfl_xor(mx, 32));
        float p[16], ss = 0.f;
        #pragma unroll
        for (int mi = 0; mi < 3; ++mi)
            #pragma unroll
            for (int r = 0; r < 4; ++r) {
                float e = __expf(acc[mi][ni][r] - mx);
                p[mi * 4 + r] = e; ss += e;
            }
        float e48 = (g == 0) ? __expf(acc[3][ni][0] - mx) : 0.f;
        p[12] = e48; p[13] = p[14] = p[15] = 0.f; ss += e48;
        ss += __shfl_xor(ss, 16);
        ss += __shfl_xor(ss, 32);
        inv[ni] = 1.f / ss;
        int q = ni * 16 + lr;
        #pragma unroll
        for (int mi = 0; mi < 4; ++mi) {
            *(unsigned int*)&P[q][mi * 16 + g * 4]     = pack2bf(p[mi * 4 + 0], p[mi * 4 + 1]);
            *(unsigned int*)&P[q][mi * 16 + g * 4 + 2] = pack2bf(p[mi * 4 + 2], p[mi * 4 + 3]);
        }
    }
    __syncthreads();

    f32x4_t oacc[2][4] = {};
    #pragma unroll
    for (int kt = 0; kt < 2; ++kt) {
        bf16x8_t va[2], pb[4];
        #pragma unroll
        for (int mt = 0; mt < 2; ++mt)
            va[mt] = *(const bf16x8_t*)&VT[mt * 16 + lr][kt * 32 + g * 8];
        #pragma unroll
        for (int nt = 0; nt < 4; ++nt)
            pb[nt] = *(const bf16x8_t*)&P[nt * 16 + lr][kt * 32 + g * 8];
        #pragma unroll
        for (int mt = 0; mt < 2; ++mt)
            #pragma unroll
            for (int nt = 0; nt < 4; ++nt)
                oacc[mt][nt] = __builtin_amdgcn_mfma_f32_16x16x32_bf16(va[mt], pb[nt], oacc[mt][nt], 0, 0, 0);
    }

    #pragma unroll
    for (int nt = 0; nt < 4; ++nt) {
        int q = nt * 16 + lr;
        if (q < 49) {
            size_t tokg = (size_t)(win0 + wloc) * 49 + q;
            unsigned short* op = outp + tokg * 192 + head * 32;
            #pragma unroll
            for (int mt = 0; mt < 2; ++mt) {
                int d0 = mt * 16 + g * 4;
                float a0 = oacc[mt][nt][0] * inv[nt], a1 = oacc[mt][nt][1] * inv[nt];
                float a2 = oacc[mt][nt][2] * inv[nt], a3 = oacc[mt][nt][3] * inv[nt];
                *(unsigned int*)(op + d0)     = pack2bf(a0, a1);
                *(unsigned int*)(op + d0 + 2) = pack2bf(a2, a3);
            }
        }
    }
}

// ---------------- host launch ----------------
extern "C" void kernel_launch(void* const* d_in, const int* in_sizes, int n_in,
                              void* d_out, int out_size, void* d_ws, size_t ws_size,
                              hipStream_t stream) {
    (void)in_sizes; (void)n_in; (void)out_size; (void)ws_size;
    const float* X     = (const float*)d_in[0];
    const float* ln1_g = (const float*)d_in[1];
    const float* ln1_b = (const float*)d_in[2];
    const float* ln2_g = (const float*)d_in[3];
    const float* ln2_b = (const float*)d_in[4];
    const float* qkv_w[2]  = { (const float*)d_in[5],  (const float*)d_in[10] };
    const float* qkv_b[2]  = { (const float*)d_in[6],  (const float*)d_in[11] };
    const float* proj_w[2] = { (const float*)d_in[7],  (const float*)d_in[12] };
    const float* proj_b[2] = { (const float*)d_in[8],  (const float*)d_in[13] };
    const float* btab[2]   = { (const float*)d_in[9],  (const float*)d_in[14] };
    const float* w1 = (const float*)d_in[15];
    const float* b1 = (const float*)d_in[16];
    const float* w2 = (const float*)d_in[17];
    const float* b2 = (const float*)d_in[18];

    char* p = (char*)d_ws;
    auto takeb = [&](size_t bytes) -> char* {
        char* r = p;
        p += (bytes + 255) & ~(size_t)255;
        return r;
    };
    auto take = [&](size_t elems) -> unsigned short* {
        return (unsigned short*)takeb(elems * 2);
    };
    unsigned short* WTq[2]; unsigned short* WTp[2];
    WTq[0] = take(576 * 192); WTp[0] = take(192 * 192);
    WTq[1] = take(576 * 192); WTp[1] = take(192 * 192);
    unsigned short* WT1 = take(768 * 192);
    unsigned short* WT2 = take(192 * 768);
    float* biasM = (float*)takeb(2 * 24576 * sizeof(float));
    unsigned short* B0 = take((size_t)NTOK * 192);            // ln1 out -> attn out -> ln2 out
    unsigned short* B1 = take((size_t)TOK_PER_CHUNK * 768);   // qkv chunk / proj out (full) / mlp hidden chunk

    auto tr = [&](const float* src, unsigned short* dst, int K, int N) {
        int n = K * N;
        wt_kernel<<<dim3((n + 255) / 256), dim3(256), 0, stream>>>(src, dst, K, N);
    };
    tr(qkv_w[0],  WTq[0], 192, 576);
    tr(proj_w[0], WTp[0], 192, 192);
    tr(qkv_w[1],  WTq[1], 192, 576);
    tr(proj_w[1], WTp[1], 192, 192);
    tr(w1, WT1, 192, 768);
    tr(w2, WT2, 768, 192);
    bias_kernel<<<dim3(96, 2), dim3(256), 0, stream>>>(btab[0], btab[1], biasM);

    float* trunk = (float*)d_out;   // f32 trunk (block-1 frame, LINEAR) lives in d_out

    for (int blk = 0; blk < 2; ++blk) {
        const float* Xin = (blk == 0) ? X : (const float*)trunk;

        if (blk == 0)
            ln_kernel<0, 0><<<dim3(NTOK / 4), dim3(256), 0, stream>>>((const void*)Xin, B0, ln1_g, ln1_b);
        else
            ln_kernel<0, 1><<<dim3(NTOK / 4), dim3(256), 0, stream>>>((const void*)Xin, B0, ln1_g, ln1_b);

        for (int c = 0; c < NCHUNK; ++c) {
            size_t row0 = (size_t)c * TOK_PER_CHUNK;
            gemm192_kernel<576, 3, EP_QKV><<<dim3((TOK_PER_CHUNK / 128) * 3), dim3(256), 0, stream>>>(
                B0 + row0 * 192, WTq[blk], qkv_b[blk], nullptr, (void*)B1, (int)row0);
            attn_kernel<<<dim3(6, WIN_PER_CHUNK), dim3(64), 0, stream>>>(
                B1, biasM + (size_t)blk * 24576, B0, c * WIN_PER_CHUNK);
        }

        // PROJ: A=B0 (attn out), residual = Xin (block 2: roll-read), out -> B1 (bf16)
        if (blk == 0)
            gemm192_kernel<192, 1, EP_PROJ1><<<dim3(NTOK / 128), dim3(256), 0, stream>>>(
                B0, WTp[blk], proj_b[blk], (const void*)Xin, (void*)B1, 0);
        else
            gemm192_kernel<192, 1, EP_PROJ2><<<dim3(NTOK / 128), dim3(256), 0, stream>>>(
                B0, WTp[blk], proj_b[blk], (const void*)Xin, (void*)B1, 0);

        // LN2: B1 (bf16 X2) -> B0
        ln_kernel<1, 0><<<dim3(NTOK / 4), dim3(256), 0, stream>>>((const void*)B1, B0, ln2_g, ln2_b);

        for (int c = 0; c < NCHUNK; ++c) {
            size_t row0 = (size_t)c * TOK_PER_CHUNK;
            gemm192_kernel<768, 4, EP_MLP1><<<dim3((TOK_PER_CHUNK / 128) * 4), dim3(256), 0, stream>>>(
                B0 + row0 * 192, WT1, b1, nullptr, (void*)B1, (int)row0);
            if (blk == 0)
                gemm768_kernel<EP_MLP2_TRUNK><<<dim3(TOK_PER_CHUNK / 128), dim3(256), 0, stream>>>(
                    B1, WT2, b2, (const void*)(B0 + row0 * 192), (void*)trunk, (int)row0);
            else
                gemm768_kernel<EP_MLP2_OUT><<<dim3(TOK_PER_CHUNK / 128), dim3(256), 0, stream>>>(
                    B1, WT2, b2, (const void*)(B0 + row0 * 192), (void*)d_out, (int)row0);
        }
    }
}

// Round 7
// 2818.823 us; speedup vs baseline: 1.7172x; 1.7172x over previous
//
#include <hip/hip_runtime.h>
#include <hip/hip_bf16.h>
#include <math.h>

// ---------------- problem constants ----------------
#define NTOK 401408              // 8*1024*49 tokens
#define NWIN 8192                // 8*1024 windows
#define NCHUNK 4
#define TOK_PER_CHUNK (NTOK / NCHUNK)   // 100352
#define WIN_PER_CHUNK (NWIN / NCHUNK)   // 2048

typedef __attribute__((ext_vector_type(8))) short bf16x8_t;
typedef __attribute__((ext_vector_type(4))) float f32x4_t;

__device__ __forceinline__ float bf2f(unsigned int u) {
    return __uint_as_float(u << 16);
}
__device__ __forceinline__ unsigned short f2bf(float f) {
    unsigned int x = __float_as_uint(f);
    x += 0x7fffu + ((x >> 16) & 1u);   // RNE
    return (unsigned short)(x >> 16);
}
__device__ __forceinline__ unsigned int pack2bf(float a, float b) {
    return (unsigned int)f2bf(a) | ((unsigned int)f2bf(b) << 16);
}

// ---------------- weight transpose + bf16 cast:  WT[n][k] = W[k][n] ----------------
__global__ void wt_kernel(const float* __restrict__ W, unsigned short* __restrict__ WT,
                          int K, int N) {
    int i = blockIdx.x * 256 + threadIdx.x;
    if (i >= N * K) return;
    int n = i / K, k = i - n * K;
    WT[i] = f2bf(W[(size_t)k * N + n]);
}

// ---------------- bias(+mask) table baked into MFMA C-fragment layout ----------------
__global__ void bias_kernel(const float* __restrict__ bt0, const float* __restrict__ bt1,
                            float* __restrict__ bm) {
    int idx = blockIdx.x * 256 + threadIdx.x;   // 0..24575
    int variant = blockIdx.y;
    const float* bt = variant ? bt1 : bt0;
    int r = idx & 3, lane = (idx >> 2) & 63, ni = (idx >> 8) & 3, mi = (idx >> 10) & 3, h = idx >> 12;
    int g = lane >> 4;
    int q = ni * 16 + (lane & 15);
    int k = mi * 16 + g * 4 + r;
    float v = 0.f;
    if (q < 49 && k < 49) {
        int qh = q / 7, qw = q - qh * 7, kh = k / 7, kw = k - kh * 7;
        v = bt[((qh - kh + 6) * 13 + (qw - kw + 6)) * 6 + h];
        if (variant) {
            int rq = 2 * (qh >= 4) + (qw >= 4), rk = 2 * (kh >= 4) + (kw >= 4);
            if (rq != rk) v -= 100.f;
        }
    }
    bm[(size_t)variant * 24576 + idx] = v;
}

// ---------------- LayerNorm over 192 channels, 1 wave / token ----------------
template<int IN_BF16, int ROLL>
__global__ __launch_bounds__(256) void ln_kernel(const void* __restrict__ in,
                                                 unsigned short* __restrict__ out,
                                                 const float* __restrict__ g,
                                                 const float* __restrict__ b) {
    int tok  = blockIdx.x * 4 + (threadIdx.x >> 6);
    int lane = threadIdx.x & 63;
    int src = tok;
    if (ROLL) {
        int win = tok / 49, p2 = tok - win * 49;
        int h = p2 / 7, w = p2 - h * 7;
        int h2 = h + 3; if (h2 >= 7) h2 -= 7;
        int w2 = w + 3; if (w2 >= 7) w2 -= 7;
        src = win * 49 + h2 * 7 + w2;
    }
    float x0, x1, x2;
    if (IN_BF16) {
        const unsigned short* p = (const unsigned short*)in + (size_t)src * 192;
        x0 = bf2f(p[lane]); x1 = bf2f(p[lane + 64]); x2 = bf2f(p[lane + 128]);
    } else {
        const float* p = (const float*)in + (size_t)src * 192;
        x0 = p[lane]; x1 = p[lane + 64]; x2 = p[lane + 128];
    }
    float s  = x0 + x1 + x2;
    float sq = x0 * x0 + x1 * x1 + x2 * x2;
    for (int o = 32; o; o >>= 1) { s += __shfl_xor(s, o); sq += __shfl_xor(sq, o); }
    float m   = s * (1.f / 192.f);
    float var = sq * (1.f / 192.f) - m * m;
    float r   = rsqrtf(var + 1e-5f);
    unsigned short* q = out + (size_t)tok * 192;
    q[lane]       = f2bf((x0 - m) * r * g[lane]       + b[lane]);
    q[lane + 64]  = f2bf((x1 - m) * r * g[lane + 64]  + b[lane + 64]);
    q[lane + 128] = f2bf((x2 - m) * r * g[lane + 128] + b[lane + 128]);
}

// ---------------- epilogue codes ----------------
#define EP_QKV        0   // + bias, Q cols pre-scaled by 1/sqrt(dh) -> bf16 (ld = NDIM)
#define EP_PROJ1      1   // + bias + f32 residual (linear) -> bf16
#define EP_PROJ2      2   // + bias + f32 residual (roll-read) -> bf16
#define EP_MLP1       3   // + bias, exact GELU -> bf16 (ld = NDIM)
#define EP_MLP2_TRUNK 4   // + bias + bf16 residual -> f32 trunk, LINEAR write
#define EP_MLP2_OUT   5   // + bias + bf16 residual -> f32 d_out with final roll (w+3, c+3)

// ---------------- unified GEMM: C[M,N] = A[M,K] @ W[K,N] + bias, fused epilogues ----
// Tile 128x96, BK=32, 4 waves (2m x 2n), per-wave 64x48 = 4x3 fragments.
// Both operands staged; LDS double-buffered (one barrier/iter); next K-slice
// register-prefetched before the barrier so loads fly under MFMA.
// Block order: y-fastest (A-row L2 reuse) + XCD chunking (grid % 8 == 0).
template<int NDIM, int KDIM, int NY, int EP>
__global__ __launch_bounds__(256) void gemm_kernel(const unsigned short* __restrict__ A,
                                                   const unsigned short* __restrict__ WT,
                                                   const float* __restrict__ bias,
                                                   const void* __restrict__ res,
                                                   void* __restrict__ out,
                                                   int row0) {
    __shared__ __align__(16) unsigned short As[2][128][40];   // +8 pad
    __shared__ __align__(16) unsigned short Bs[2][96][40];
    int tid = threadIdx.x;
    int nwg = gridDim.x;
    int id = blockIdx.x;
    int id2 = (id & 7) * (nwg >> 3) + (id >> 3);    // XCD-chunked (nwg % 8 == 0)
    int by = id2 % NY, bx = id2 / NY;               // y fastest
    int rowBase = bx * 128;
    int colBase = by * 96;

    // staging decomposition: A = 512 uint4 chunks (2/thread), B = 384 (1.5/thread)
    int cr = tid >> 2, cp = (tid & 3) * 8;          // chunk row / elem offset
    const unsigned short* Ab = A  + (size_t)rowBase * KDIM + cp;
    const unsigned short* Bb = WT + (size_t)colBase * KDIM + cp;

    uint4 a0, a1, b0, b1;
    const int NT = KDIM / 32;

    #define LOADK(k0)                                                          \
        do {                                                                   \
            a0 = *(const uint4*)(Ab + (size_t)cr * KDIM + (k0));               \
            a1 = *(const uint4*)(Ab + (size_t)(cr + 64) * KDIM + (k0));        \
            b0 = *(const uint4*)(Bb + (size_t)cr * KDIM + (k0));               \
            if (tid < 128) b1 = *(const uint4*)(Bb + (size_t)(cr + 64) * KDIM + (k0)); \
        } while (0)
    #define WRITEK(buf)                                                        \
        do {                                                                   \
            *(uint4*)&As[buf][cr][cp] = a0;                                    \
            *(uint4*)&As[buf][cr + 64][cp] = a1;                               \
            *(uint4*)&Bs[buf][cr][cp] = b0;                                    \
            if (tid < 128) *(uint4*)&Bs[buf][cr + 64][cp] = b1;                \
        } while (0)

    LOADK(0);
    WRITEK(0);

    int wave = tid >> 6, lane = tid & 63;
    int wm = wave >> 1, wn = wave & 1;
    int kq = lane >> 4, lr = lane & 15;

    f32x4_t acc[4][3] = {};
    for (int kt = 0; kt < NT; ++kt) {
        if (kt + 1 < NT) LOADK((kt + 1) * 32);      // in flight across barrier+MFMA
        __syncthreads();                            // buf[kt&1] fully written
        int buf = kt & 1;
        bf16x8_t afr[4], bfr[3];
        #pragma unroll
        for (int mi = 0; mi < 4; ++mi)
            afr[mi] = *(const bf16x8_t*)&As[buf][wm * 64 + mi * 16 + lr][kq * 8];
        #pragma unroll
        for (int ni = 0; ni < 3; ++ni)
            bfr[ni] = *(const bf16x8_t*)&Bs[buf][wn * 48 + ni * 16 + lr][kq * 8];
        #pragma unroll
        for (int mi = 0; mi < 4; ++mi)
            #pragma unroll
            for (int ni = 0; ni < 3; ++ni)
                acc[mi][ni] = __builtin_amdgcn_mfma_f32_16x16x32_bf16(
                    afr[mi], bfr[ni], acc[mi][ni], 0, 0, 0);
        if (kt + 1 < NT) WRITEK((kt + 1) & 1);      // other buffer: no race with readers
    }
    #undef LOADK
    #undef WRITEK

    const float* resf = (const float*)res;
    const unsigned short* resb = (const unsigned short*)res;
    #pragma unroll
    for (int mi = 0; mi < 4; ++mi) {
        #pragma unroll
        for (int ni = 0; ni < 3; ++ni) {
            int col = colBase + wn * 48 + ni * 16 + lr;
            float bcol = bias[col];
            #pragma unroll
            for (int r = 0; r < 4; ++r) {
                int rloc = rowBase + wm * 64 + mi * 16 + kq * 4 + r;
                float v = acc[mi][ni][r] + bcol;
                if (EP == EP_QKV) {
                    if (colBase < 192) v *= 0.17677669529663687f;   // pre-scale Q
                    ((unsigned short*)out)[(size_t)rloc * NDIM + col] = f2bf(v);
                } else if (EP == EP_PROJ1) {
                    v += resf[(size_t)rloc * 192 + col];
                    ((unsigned short*)out)[(size_t)rloc * 192 + col] = f2bf(v);
                } else if (EP == EP_PROJ2) {
                    int win = rloc / 49, p2 = rloc - win * 49;
                    int h = p2 / 7, w = p2 - h * 7;
                    int h2 = h + 3; if (h2 >= 7) h2 -= 7;
                    int w2 = w + 3; if (w2 >= 7) w2 -= 7;
                    v += resf[((size_t)win * 49 + h2 * 7 + w2) * 192 + col];
                    ((unsigned short*)out)[(size_t)rloc * 192 + col] = f2bf(v);
                } else if (EP == EP_MLP1) {
                    float gl = 0.5f * v * (1.f + erff(v * 0.70710678118654752f));
                    ((unsigned short*)out)[(size_t)rloc * NDIM + col] = f2bf(gl);
                } else if (EP == EP_MLP2_TRUNK) {
                    v += bf2f((unsigned int)resb[(size_t)rloc * 192 + col]);
                    int grow = row0 + rloc;
                    ((float*)out)[(size_t)grow * 192 + col] = v;   // linear trunk
                } else {  // EP_MLP2_OUT
                    v += bf2f((unsigned int)resb[(size_t)rloc * 192 + col]);
                    int grow = row0 + rloc;
                    int win = grow / 49, p2 = grow - win * 49;
                    int h = p2 / 7, w = p2 - h * 7;
                    int w2 = w + 3; if (w2 >= 7) w2 -= 7;
                    int c2 = col + 3; if (c2 >= 192) c2 -= 192;
                    ((float*)out)[((size_t)win * 49 + h * 7 + w2) * 192 + c2] = v;
                }
            }
        }
    }
}

// ---------------- MFMA window attention: 1 wave per (head, window) ----------------
__global__ __launch_bounds__(64) void attn_kernel(const unsigned short* __restrict__ qkv,
                                                  const float* __restrict__ bm,  // [6][4][4][64][4]
                                                  unsigned short* __restrict__ outp,
                                                  int win0) {
    __shared__ unsigned short P[64][72];
    __shared__ unsigned short VT[32][72];
    int head = blockIdx.x, wloc = blockIdx.y;
    int lane = threadIdx.x;
    int g = lane >> 4, lr = lane & 15;
    const unsigned short* base = qkv + (size_t)wloc * 49 * 576;

    // stage V^T (tok>=49 -> zeros)
    for (int i = lane; i < 256; i += 64) {
        int tok = i >> 2, seg = i & 3;
        uint4 u = make_uint4(0u, 0u, 0u, 0u);
        if (tok < 49)
            u = *(const uint4*)(base + (size_t)tok * 576 + 384 + head * 32 + seg * 8);
        const unsigned short* us = (const unsigned short*)&u;
        #pragma unroll
        for (int j = 0; j < 8; ++j) VT[seg * 8 + j][tok] = us[j];
    }

    bf16x8_t kf[4], qf[4];
    #pragma unroll
    for (int mi = 0; mi < 4; ++mi) {
        int tok = mi * 16 + lr; if (tok > 48) tok = 48;
        kf[mi] = *(const bf16x8_t*)(base + (size_t)tok * 576 + 192 + head * 32 + g * 8);
    }
    #pragma unroll
    for (int ni = 0; ni < 4; ++ni) {
        int tok = ni * 16 + lr; if (tok > 48) tok = 48;
        qf[ni] = *(const bf16x8_t*)(base + (size_t)tok * 576 + head * 32 + g * 8);
    }

    const float* bmh = bm + (size_t)head * 4096;
    f32x4_t acc[4][4];
    #pragma unroll
    for (int mi = 0; mi < 4; ++mi)
        #pragma unroll
        for (int ni = 0; ni < 4; ++ni)
            acc[mi][ni] = *(const f32x4_t*)(bmh + ((mi * 4 + ni) * 64 + lane) * 4);
    #pragma unroll
    for (int mi = 0; mi < 4; ++mi)
        #pragma unroll
        for (int ni = 0; ni < 4; ++ni)
            acc[mi][ni] = __builtin_amdgcn_mfma_f32_16x16x32_bf16(kf[mi], qf[ni], acc[mi][ni], 0, 0, 0);

    float inv[4];
    #pragma unroll
    for (int ni = 0; ni < 4; ++ni) {
        float mx = -1e30f;
        #pragma unroll
        for (int mi = 0; mi < 3; ++mi)
            #pragma unroll
            for (int r = 0; r < 4; ++r) mx = fmaxf(mx, acc[mi][ni][r]);
        mx = fmaxf(mx, (g == 0) ? acc[3][ni][0] : -1e30f);
        mx = fmaxf(mx, __shfl_xor(mx, 16));
        mx = fmaxf(mx, __shfl_xor(mx, 32));
        float p[16], ss = 0.f;
        #pragma unroll
        for (int mi = 0; mi < 3; ++mi)
            #pragma unroll
            for (int r = 0; r < 4; ++r) {
                float e = __expf(acc[mi][ni][r] - mx);
                p[mi * 4 + r] = e; ss += e;
            }
        float e48 = (g == 0) ? __expf(acc[3][ni][0] - mx) : 0.f;
        p[12] = e48; p[13] = p[14] = p[15] = 0.f; ss += e48;
        ss += __shfl_xor(ss, 16);
        ss += __shfl_xor(ss, 32);
        inv[ni] = 1.f / ss;
        int q = ni * 16 + lr;
        #pragma unroll
        for (int mi = 0; mi < 4; ++mi) {
            *(unsigned int*)&P[q][mi * 16 + g * 4]     = pack2bf(p[mi * 4 + 0], p[mi * 4 + 1]);
            *(unsigned int*)&P[q][mi * 16 + g * 4 + 2] = pack2bf(p[mi * 4 + 2], p[mi * 4 + 3]);
        }
    }
    __syncthreads();

    f32x4_t oacc[2][4] = {};
    #pragma unroll
    for (int kt = 0; kt < 2; ++kt) {
        bf16x8_t va[2], pb[4];
        #pragma unroll
        for (int mt = 0; mt < 2; ++mt)
            va[mt] = *(const bf16x8_t*)&VT[mt * 16 + lr][kt * 32 + g * 8];
        #pragma unroll
        for (int nt = 0; nt < 4; ++nt)
            pb[nt] = *(const bf16x8_t*)&P[nt * 16 + lr][kt * 32 + g * 8];
        #pragma unroll
        for (int mt = 0; mt < 2; ++mt)
            #pragma unroll
            for (int nt = 0; nt < 4; ++nt)
                oacc[mt][nt] = __builtin_amdgcn_mfma_f32_16x16x32_bf16(va[mt], pb[nt], oacc[mt][nt], 0, 0, 0);
    }

    #pragma unroll
    for (int nt = 0; nt < 4; ++nt) {
        int q = nt * 16 + lr;
        if (q < 49) {
            size_t tokg = (size_t)(win0 + wloc) * 49 + q;
            unsigned short* op = outp + tokg * 192 + head * 32;
            #pragma unroll
            for (int mt = 0; mt < 2; ++mt) {
                int d0 = mt * 16 + g * 4;
                float a0 = oacc[mt][nt][0] * inv[nt], a1 = oacc[mt][nt][1] * inv[nt];
                float a2 = oacc[mt][nt][2] * inv[nt], a3 = oacc[mt][nt][3] * inv[nt];
                *(unsigned int*)(op + d0)     = pack2bf(a0, a1);
                *(unsigned int*)(op + d0 + 2) = pack2bf(a2, a3);
            }
        }
    }
}

// ---------------- host launch ----------------
extern "C" void kernel_launch(void* const* d_in, const int* in_sizes, int n_in,
                              void* d_out, int out_size, void* d_ws, size_t ws_size,
                              hipStream_t stream) {
    (void)in_sizes; (void)n_in; (void)out_size; (void)ws_size;
    const float* X     = (const float*)d_in[0];
    const float* ln1_g = (const float*)d_in[1];
    const float* ln1_b = (const float*)d_in[2];
    const float* ln2_g = (const float*)d_in[3];
    const float* ln2_b = (const float*)d_in[4];
    const float* qkv_w[2]  = { (const float*)d_in[5],  (const float*)d_in[10] };
    const float* qkv_b[2]  = { (const float*)d_in[6],  (const float*)d_in[11] };
    const float* proj_w[2] = { (const float*)d_in[7],  (const float*)d_in[12] };
    const float* proj_b[2] = { (const float*)d_in[8],  (const float*)d_in[13] };
    const float* btab[2]   = { (const float*)d_in[9],  (const float*)d_in[14] };
    const float* w1 = (const float*)d_in[15];
    const float* b1 = (const float*)d_in[16];
    const float* w2 = (const float*)d_in[17];
    const float* b2 = (const float*)d_in[18];

    char* p = (char*)d_ws;
    auto takeb = [&](size_t bytes) -> char* {
        char* r = p;
        p += (bytes + 255) & ~(size_t)255;
        return r;
    };
    auto take = [&](size_t elems) -> unsigned short* {
        return (unsigned short*)takeb(elems * 2);
    };
    unsigned short* WTq[2]; unsigned short* WTp[2];
    WTq[0] = take(576 * 192); WTp[0] = take(192 * 192);
    WTq[1] = take(576 * 192); WTp[1] = take(192 * 192);
    unsigned short* WT1 = take(768 * 192);
    unsigned short* WT2 = take(192 * 768);
    float* biasM = (float*)takeb(2 * 24576 * sizeof(float));
    unsigned short* B0 = take((size_t)NTOK * 192);            // ln1 out -> attn out -> ln2 out
    unsigned short* B1 = take((size_t)TOK_PER_CHUNK * 768);   // qkv chunk / proj out (full) / mlp hidden chunk

    auto tr = [&](const float* src, unsigned short* dst, int K, int N) {
        int n = K * N;
        wt_kernel<<<dim3((n + 255) / 256), dim3(256), 0, stream>>>(src, dst, K, N);
    };
    tr(qkv_w[0],  WTq[0], 192, 576);
    tr(proj_w[0], WTp[0], 192, 192);
    tr(qkv_w[1],  WTq[1], 192, 576);
    tr(proj_w[1], WTp[1], 192, 192);
    tr(w1, WT1, 192, 768);
    tr(w2, WT2, 768, 192);
    bias_kernel<<<dim3(96, 2), dim3(256), 0, stream>>>(btab[0], btab[1], biasM);

    float* trunk = (float*)d_out;   // f32 trunk (block-1 frame, LINEAR) lives in d_out

    for (int blk = 0; blk < 2; ++blk) {
        const float* Xin = (blk == 0) ? X : (const float*)trunk;

        if (blk == 0)
            ln_kernel<0, 0><<<dim3(NTOK / 4), dim3(256), 0, stream>>>((const void*)Xin, B0, ln1_g, ln1_b);
        else
            ln_kernel<0, 1><<<dim3(NTOK / 4), dim3(256), 0, stream>>>((const void*)Xin, B0, ln1_g, ln1_b);

        for (int c = 0; c < NCHUNK; ++c) {
            size_t row0 = (size_t)c * TOK_PER_CHUNK;
            gemm_kernel<576, 192, 6, EP_QKV><<<dim3((TOK_PER_CHUNK / 128) * 6), dim3(256), 0, stream>>>(
                B0 + row0 * 192, WTq[blk], qkv_b[blk], nullptr, (void*)B1, (int)row0);
            attn_kernel<<<dim3(6, WIN_PER_CHUNK), dim3(64), 0, stream>>>(
                B1, biasM + (size_t)blk * 24576, B0, c * WIN_PER_CHUNK);
        }

        // PROJ: A=B0 (attn out), residual = Xin (block 2: roll-read), out -> B1 (bf16)
        if (blk == 0)
            gemm_kernel<192, 192, 2, EP_PROJ1><<<dim3((NTOK / 128) * 2), dim3(256), 0, stream>>>(
                B0, WTp[blk], proj_b[blk], (const void*)Xin, (void*)B1, 0);
        else
            gemm_kernel<192, 192, 2, EP_PROJ2><<<dim3((NTOK / 128) * 2), dim3(256), 0, stream>>>(
                B0, WTp[blk], proj_b[blk], (const void*)Xin, (void*)B1, 0);

        // LN2: B1 (bf16 X2) -> B0
        ln_kernel<1, 0><<<dim3(NTOK / 4), dim3(256), 0, stream>>>((const void*)B1, B0, ln2_g, ln2_b);

        for (int c = 0; c < NCHUNK; ++c) {
            size_t row0 = (size_t)c * TOK_PER_CHUNK;
            gemm_kernel<768, 192, 8, EP_MLP1><<<dim3((TOK_PER_CHUNK / 128) * 8), dim3(256), 0, stream>>>(
                B0 + row0 * 192, WT1, b1, nullptr, (void*)B1, (int)row0);
            if (blk == 0)
                gemm_kernel<192, 768, 2, EP_MLP2_TRUNK><<<dim3((TOK_PER_CHUNK / 128) * 2), dim3(256), 0, stream>>>(
                    B1, WT2, b2, (const void*)(B0 + row0 * 192), (void*)trunk, (int)row0);
            else
                gemm_kernel<192, 768, 2, EP_MLP2_OUT><<<dim3((TOK_PER_CHUNK / 128) * 2), dim3(256), 0, stream>>>(
                    B1, WT2, b2, (const void*)(B0 + row0 * 192), (void*)d_out, (int)row0);
        }
    }
}